// Round 2
// baseline (3113.723 us; speedup 1.0000x reference)
//
#include <hip/hip_runtime.h>
#include <hip/hip_bf16.h>

#define NB   4
#define NC   512
#define NCI  256
#define NPOS 12544   // 16*28*28
#define NPP  1568    // 8*14*14

// ---------------------------------------------------------------------------
// conv_in: out[b][n][o] = sum_c x[b][c][n] * w[o][c] + bias[o]
// x: (B, C, N) n-fastest; w: (OC=256, C) c-fastest; out: (B, N, 256)
// 64x64 tile, BK=16, k-major LDS, 4x4 micro-tile, float4 LDS reads.
// ---------------------------------------------------------------------------
__global__ __launch_bounds__(256) void conv_in(const float* __restrict__ x,
                                               const float* __restrict__ wgt,
                                               const float* __restrict__ bias,
                                               float* __restrict__ out) {
  __shared__ float Xs[16][64];  // [k][n]
  __shared__ float Ws[16][64];  // [k][o]
  const int b  = blockIdx.z;
  const int n0 = blockIdx.x * 64;
  const int o0 = blockIdx.y * 64;
  const int tid = threadIdx.x;
  const int tr = tid >> 4;           // -> n group
  const int tc = tid & 15;           // -> o group (fastest out dim)
  const int lk  = tid >> 4;          // Xs loader: k row
  const int ln4 = (tid & 15) << 2;   // Xs loader: n quad
  const int lo  = tid >> 2;          // Ws loader: o row
  const int lk4 = (tid & 3) << 2;    // Ws loader: k quad
  float acc[4][4] = {};
  for (int k0 = 0; k0 < NC; k0 += 16) {
    __syncthreads();
    *(float4*)&Xs[lk][ln4] =
        *(const float4*)(x + ((size_t)b * NC + k0 + lk) * NPOS + n0 + ln4);
    float4 wv = *(const float4*)(wgt + (size_t)(o0 + lo) * NC + k0 + lk4);
    Ws[lk4 + 0][lo] = wv.x; Ws[lk4 + 1][lo] = wv.y;
    Ws[lk4 + 2][lo] = wv.z; Ws[lk4 + 3][lo] = wv.w;
    __syncthreads();
#pragma unroll
    for (int k = 0; k < 16; ++k) {
      float4 a4 = *(const float4*)&Xs[k][tr << 2];
      float4 w4 = *(const float4*)&Ws[k][tc << 2];
      const float av[4] = {a4.x, a4.y, a4.z, a4.w};
      const float wvv[4] = {w4.x, w4.y, w4.z, w4.w};
#pragma unroll
      for (int i = 0; i < 4; ++i)
#pragma unroll
        for (int j = 0; j < 4; ++j) acc[i][j] = fmaf(av[i], wvv[j], acc[i][j]);
    }
  }
  float4 bv = *(const float4*)(bias + o0 + (tc << 2));
  const float bvv[4] = {bv.x, bv.y, bv.z, bv.w};
#pragma unroll
  for (int i = 0; i < 4; ++i) {
    float4 ov = make_float4(acc[i][0] + bvv[0], acc[i][1] + bvv[1],
                            acc[i][2] + bvv[2], acc[i][3] + bvv[3]);
    *(float4*)(out + ((size_t)b * NPOS + n0 + (tr << 2) + i) * NCI + o0 + (tc << 2)) = ov;
  }
}

// ---------------------------------------------------------------------------
// pool2: MaxPool3d(2,2) over (t,h,w). full: (B,N,256) -> dst: (B,N',256)
// ---------------------------------------------------------------------------
__global__ __launch_bounds__(256) void pool2(const float* __restrict__ full,
                                             float* __restrict__ dst) {
  const int m = blockIdx.x;
  const int b = blockIdx.y;
  const int o = threadIdx.x;
  const int tp = m / 196;
  const int rr = m % 196;
  const int hp = rr / 14;
  const int wp = rr % 14;
  const size_t base = (size_t)b * NPOS * NCI;
  float best = -1e30f;
#pragma unroll
  for (int dt = 0; dt < 2; ++dt)
#pragma unroll
    for (int dh = 0; dh < 2; ++dh)
#pragma unroll
      for (int dw = 0; dw < 2; ++dw) {
        int n = (2 * tp + dt) * 784 + (2 * hp + dh) * 28 + (2 * wp + dw);
        best = fmaxf(best, full[base + (size_t)n * NCI + o]);
      }
  dst[((size_t)b * NPP + m) * NCI + o] = best;
}

// ---------------------------------------------------------------------------
// attn: flash-style. theta:(B,N,256) phi:(B,N',256) g:(B,N',256) -> y:(B,N,256)
// Per block: 64 q rows. kv tiles of 64. Online softmax (max-subtracted).
// ---------------------------------------------------------------------------
__global__ __launch_bounds__(256) void attn(const float* __restrict__ theta,
                                            const float* __restrict__ phi,
                                            const float* __restrict__ g,
                                            float* __restrict__ y) {
  __shared__ float th_ch[32][64];   // [k][q]
  __shared__ float ph_ch[32][64];   // [k][m]
  __shared__ float p_lds[64][68];   // [q][m], pad 68 keeps f4 reads conflict-free
  const int b  = blockIdx.y;
  const int n0 = blockIdx.x * 64;
  const int tid = threadIdx.x;
  const int tr = tid >> 4;          // q group (rows 4tr..4tr+3)
  const int tc = tid & 15;          // m group (scores) / c group (PV)
  const int lq  = tid >> 2;         // loader row 0..63
  const int lk8 = (tid & 3) << 3;   // loader k offset 0,8,16,24
  const float* thb = theta + (size_t)b * NPOS * NCI;
  const float* phb = phi + (size_t)b * NPP * NCI;
  const float* gb  = g + (size_t)b * NPP * NCI;

  float y_acc[4][4][4];             // [i][u][v]: c = 64u + 4tc + v
  float run_max[4], run_sum[4];
#pragma unroll
  for (int i = 0; i < 4; ++i) {
    run_max[i] = -1e30f; run_sum[i] = 0.f;
#pragma unroll
    for (int u = 0; u < 4; ++u)
#pragma unroll
      for (int v = 0; v < 4; ++v) y_acc[i][u][v] = 0.f;
  }

  for (int m0 = 0; m0 < NPP; m0 += 64) {
    float s[4][4];
#pragma unroll
    for (int i = 0; i < 4; ++i)
#pragma unroll
      for (int j = 0; j < 4; ++j) s[i][j] = 0.f;

    const int mload = (m0 + lq < NPP) ? m0 + lq : NPP - 1;
    for (int c0 = 0; c0 < NCI; c0 += 32) {
      __syncthreads();
      {
        const float* st = thb + (size_t)(n0 + lq) * NCI + c0 + lk8;
        float4 t0 = *(const float4*)(st);
        float4 t1 = *(const float4*)(st + 4);
        th_ch[lk8 + 0][lq] = t0.x; th_ch[lk8 + 1][lq] = t0.y;
        th_ch[lk8 + 2][lq] = t0.z; th_ch[lk8 + 3][lq] = t0.w;
        th_ch[lk8 + 4][lq] = t1.x; th_ch[lk8 + 5][lq] = t1.y;
        th_ch[lk8 + 6][lq] = t1.z; th_ch[lk8 + 7][lq] = t1.w;
        const float* sp = phb + (size_t)mload * NCI + c0 + lk8;
        float4 p0 = *(const float4*)(sp);
        float4 p1 = *(const float4*)(sp + 4);
        ph_ch[lk8 + 0][lq] = p0.x; ph_ch[lk8 + 1][lq] = p0.y;
        ph_ch[lk8 + 2][lq] = p0.z; ph_ch[lk8 + 3][lq] = p0.w;
        ph_ch[lk8 + 4][lq] = p1.x; ph_ch[lk8 + 5][lq] = p1.y;
        ph_ch[lk8 + 6][lq] = p1.z; ph_ch[lk8 + 7][lq] = p1.w;
      }
      __syncthreads();
#pragma unroll
      for (int k = 0; k < 32; ++k) {
        float4 a4 = *(const float4*)&th_ch[k][tr << 2];
        float4 b4 = *(const float4*)&ph_ch[k][tc << 2];
        const float av[4] = {a4.x, a4.y, a4.z, a4.w};
        const float bvv[4] = {b4.x, b4.y, b4.z, b4.w};
#pragma unroll
        for (int i = 0; i < 4; ++i)
#pragma unroll
          for (int j = 0; j < 4; ++j) s[i][j] = fmaf(av[i], bvv[j], s[i][j]);
      }
    }
    if (m0 + 64 > NPP) {  // tail mask: invalid kv columns -> -inf
#pragma unroll
      for (int j = 0; j < 4; ++j)
        if (m0 + (tc << 2) + j >= NPP) {
#pragma unroll
          for (int i = 0; i < 4; ++i) s[i][j] = -1e30f;
        }
    }
    // online softmax update (rows owned by 16 consecutive lanes: shfl width 16)
    float p[4][4];
#pragma unroll
    for (int i = 0; i < 4; ++i) {
      float tm = fmaxf(fmaxf(s[i][0], s[i][1]), fmaxf(s[i][2], s[i][3]));
#pragma unroll
      for (int off = 8; off >= 1; off >>= 1) tm = fmaxf(tm, __shfl_xor(tm, off, 16));
      float nm = fmaxf(run_max[i], tm);
      float sc = __expf(run_max[i] - nm);
      float ps = 0.f;
#pragma unroll
      for (int j = 0; j < 4; ++j) { p[i][j] = __expf(s[i][j] - nm); ps += p[i][j]; }
#pragma unroll
      for (int off = 8; off >= 1; off >>= 1) ps += __shfl_xor(ps, off, 16);
      run_sum[i] = run_sum[i] * sc + ps;
      run_max[i] = nm;
#pragma unroll
      for (int u = 0; u < 4; ++u)
#pragma unroll
        for (int v = 0; v < 4; ++v) y_acc[i][u][v] *= sc;
    }
#pragma unroll
    for (int i = 0; i < 4; ++i)
#pragma unroll
      for (int j = 0; j < 4; ++j) p_lds[(tr << 2) + i][(tc << 2) + j] = p[i][j];
    __syncthreads();
    // PV: y[q][c] += p[q][m] * g[m][c]
    for (int mm4 = 0; mm4 < 64; mm4 += 4) {
      float4 P4[4];
#pragma unroll
      for (int i = 0; i < 4; ++i) P4[i] = *(const float4*)&p_lds[(tr << 2) + i][mm4];
      const float Pv[4][4] = {{P4[0].x, P4[0].y, P4[0].z, P4[0].w},
                              {P4[1].x, P4[1].y, P4[1].z, P4[1].w},
                              {P4[2].x, P4[2].y, P4[2].z, P4[2].w},
                              {P4[3].x, P4[3].y, P4[3].z, P4[3].w}};
#pragma unroll
      for (int t = 0; t < 4; ++t) {
        int m = m0 + mm4 + t;
        int mr = m < NPP ? m : NPP - 1;     // p==0 for masked m
        const float* grow = gb + (size_t)mr * NCI + (tc << 2);
#pragma unroll
        for (int u = 0; u < 4; ++u) {
          float4 g4 = *(const float4*)(grow + (u << 6));
          const float gv[4] = {g4.x, g4.y, g4.z, g4.w};
#pragma unroll
          for (int i = 0; i < 4; ++i)
#pragma unroll
            for (int v = 0; v < 4; ++v)
              y_acc[i][u][v] = fmaf(Pv[i][t], gv[v], y_acc[i][u][v]);
        }
      }
    }
  }
#pragma unroll
  for (int i = 0; i < 4; ++i) {
    float inv = 1.f / run_sum[i];
    float* yrow = y + ((size_t)b * NPOS + n0 + (tr << 2) + i) * NCI;
#pragma unroll
    for (int u = 0; u < 4; ++u) {
      float4 ov = make_float4(y_acc[i][u][0] * inv, y_acc[i][u][1] * inv,
                              y_acc[i][u][2] * inv, y_acc[i][u][3] * inv);
      *(float4*)(yrow + (u << 6) + (tc << 2)) = ov;
    }
  }
}

// ---------------------------------------------------------------------------
// conv_out: out[b][o][n] = sum_ci w[o][ci] * y[b][n][ci] + bias[o]
// w: (512,256) ci-fastest; y: (B,N,256); out: (B,512,N)
// ---------------------------------------------------------------------------
__global__ __launch_bounds__(256) void conv_out(const float* __restrict__ wgt,
                                                const float* __restrict__ yv,
                                                const float* __restrict__ bias,
                                                float* __restrict__ out) {
  __shared__ float As[16][64];  // [k][o]
  __shared__ float Bs[16][64];  // [k][n]
  const int b  = blockIdx.z;
  const int n0 = blockIdx.x * 64;
  const int o0 = blockIdx.y * 64;
  const int tid = threadIdx.x;
  const int tr = tid >> 4;           // -> o group
  const int tc = tid & 15;           // -> n group (fastest out dim)
  const int lr  = tid >> 2;          // row 0..63
  const int lk4 = (tid & 3) << 2;
  float acc[4][4] = {};
  for (int k0 = 0; k0 < NCI; k0 += 16) {
    __syncthreads();
    float4 wv = *(const float4*)(wgt + (size_t)(o0 + lr) * NCI + k0 + lk4);
    As[lk4 + 0][lr] = wv.x; As[lk4 + 1][lr] = wv.y;
    As[lk4 + 2][lr] = wv.z; As[lk4 + 3][lr] = wv.w;
    float4 yv4 = *(const float4*)(yv + ((size_t)b * NPOS + n0 + lr) * NCI + k0 + lk4);
    Bs[lk4 + 0][lr] = yv4.x; Bs[lk4 + 1][lr] = yv4.y;
    Bs[lk4 + 2][lr] = yv4.z; Bs[lk4 + 3][lr] = yv4.w;
    __syncthreads();
#pragma unroll
    for (int k = 0; k < 16; ++k) {
      float4 a4 = *(const float4*)&As[k][tr << 2];
      float4 b4 = *(const float4*)&Bs[k][tc << 2];
      const float av[4] = {a4.x, a4.y, a4.z, a4.w};
      const float bvv[4] = {b4.x, b4.y, b4.z, b4.w};
#pragma unroll
      for (int i = 0; i < 4; ++i)
#pragma unroll
        for (int j = 0; j < 4; ++j) acc[i][j] = fmaf(av[i], bvv[j], acc[i][j]);
    }
  }
#pragma unroll
  for (int i = 0; i < 4; ++i) {
    float bb = bias[o0 + (tr << 2) + i];
    float4 ov = make_float4(acc[i][0] + bb, acc[i][1] + bb,
                            acc[i][2] + bb, acc[i][3] + bb);
    *(float4*)(out + ((size_t)b * NC + o0 + (tr << 2) + i) * NPOS + n0 + (tc << 2)) = ov;
  }
}

// ---------------------------------------------------------------------------
// bn_stats: per-channel mean/var over (b,n) -> scale/shift (f64 accumulation)
// ---------------------------------------------------------------------------
__global__ __launch_bounds__(256) void bn_stats(const float* __restrict__ wy,
                                                const float* __restrict__ gamma,
                                                const float* __restrict__ beta,
                                                float* __restrict__ stats) {
  const int o = blockIdx.x;
  const int tid = threadIdx.x;
  double s = 0.0, ss = 0.0;
  for (int b = 0; b < NB; ++b) {
    const float* base = wy + ((size_t)b * NC + o) * NPOS;
    for (int n = tid; n < NPOS; n += 256) {
      float v = base[n];
      s += v;
      ss += (double)v * v;
    }
  }
  __shared__ double sd[256];
  __shared__ double ssd[256];
  sd[tid] = s; ssd[tid] = ss;
  __syncthreads();
  for (int w = 128; w > 0; w >>= 1) {
    if (tid < w) { sd[tid] += sd[tid + w]; ssd[tid] += ssd[tid + w]; }
    __syncthreads();
  }
  if (tid == 0) {
    const double M = (double)NB * NPOS;
    double mean = sd[0] / M;
    double var = ssd[0] / M - mean * mean;
    double inv = 1.0 / sqrt(var + 1e-5);
    float scale = (float)inv * gamma[o];
    float shift = beta[o] - (float)mean * scale;
    stats[o] = scale;
    stats[NC + o] = shift;
  }
}

// ---------------------------------------------------------------------------
// bn_apply: out = out*scale[o] + shift[o] + x  (in place on d_out)
// ---------------------------------------------------------------------------
__global__ __launch_bounds__(256) void bn_apply(float* __restrict__ out,
                                                const float* __restrict__ x,
                                                const float* __restrict__ stats) {
  const int bo = blockIdx.x;       // 0..2047 == (b*512+o)
  const int o = bo & (NC - 1);
  const float scale = stats[o];
  const float shift = stats[NC + o];
  const size_t base = (size_t)bo * NPOS;
  for (int n4 = (int)threadIdx.x * 4; n4 < NPOS; n4 += 256 * 4) {
    float4 v = *(const float4*)(out + base + n4);
    float4 xv = *(const float4*)(x + base + n4);
    v.x = v.x * scale + shift + xv.x;
    v.y = v.y * scale + shift + xv.y;
    v.z = v.z * scale + shift + xv.z;
    v.w = v.w * scale + shift + xv.w;
    *(float4*)(out + base + n4) = v;
  }
}

// ---------------------------------------------------------------------------
extern "C" void kernel_launch(void* const* d_in, const int* in_sizes, int n_in,
                              void* d_out, int out_size, void* d_ws, size_t ws_size,
                              hipStream_t stream) {
  const float* x     = (const float*)d_in[0];
  const float* g_w   = (const float*)d_in[1];
  const float* g_b   = (const float*)d_in[2];
  const float* th_w  = (const float*)d_in[3];
  const float* th_b  = (const float*)d_in[4];
  const float* ph_w  = (const float*)d_in[5];
  const float* ph_b  = (const float*)d_in[6];
  const float* W_w   = (const float*)d_in[7];
  const float* W_b   = (const float*)d_in[8];
  const float* gamma = (const float*)d_in[9];
  const float* beta  = (const float*)d_in[10];
  float* out = (float*)d_out;
  float* ws  = (float*)d_ws;

  const size_t SZ_BNC = (size_t)NB * NPOS * NCI;  // 12,845,056
  const size_t SZ_BPC = (size_t)NB * NPP * NCI;   //  1,605,632
  float* theta  = ws;
  float* tmp    = ws + SZ_BNC;          // gfull/phifull scratch, then y
  float* gbuf   = ws + 2 * SZ_BNC;
  float* phibuf = gbuf + SZ_BPC;
  float* stats  = phibuf + SZ_BPC;
  float* y = tmp;

  dim3 blk(256);
  dim3 gridC(NPOS / 64, NCI / 64, NB);     // (196, 4, 4)
  conv_in<<<gridC, blk, 0, stream>>>(x, th_w, th_b, theta);
  conv_in<<<gridC, blk, 0, stream>>>(x, g_w, g_b, tmp);
  pool2<<<dim3(NPP, NB), blk, 0, stream>>>(tmp, gbuf);
  conv_in<<<gridC, blk, 0, stream>>>(x, ph_w, ph_b, tmp);
  pool2<<<dim3(NPP, NB), blk, 0, stream>>>(tmp, phibuf);
  attn<<<dim3(NPOS / 64, NB), blk, 0, stream>>>(theta, phibuf, gbuf, y);
  conv_out<<<dim3(NPOS / 64, NC / 64, NB), blk, 0, stream>>>(W_w, y, W_b, out);
  bn_stats<<<dim3(NC), blk, 0, stream>>>(out, gamma, beta, stats);
  bn_apply<<<dim3(NB * NC), blk, 0, stream>>>(out, x, stats);
}

// Round 3
// 1522.614 us; speedup vs baseline: 2.0450x; 2.0450x over previous
//
#include <hip/hip_runtime.h>
#include <hip/hip_bf16.h>

#define NB   4
#define NC   512
#define NCI  256
#define NPOS 12544   // 16*28*28
#define NPP  1568    // 8*14*14

typedef __attribute__((ext_vector_type(8))) short bf16x8;
typedef __attribute__((ext_vector_type(4))) short s16x4;
typedef __attribute__((ext_vector_type(4))) float f32x4;

__device__ __forceinline__ short f2bf(float f) {
  union { __hip_bfloat16 b; short s; } u;
  u.b = __float2bfloat16(f);
  return u.s;
}
__device__ __forceinline__ float bf2f(short s) {
  union { short s; __hip_bfloat16 b; } u;
  u.s = s;
  return __bfloat162float(u.b);
}

#define MFMA16(a, b, c) __builtin_amdgcn_mfma_f32_16x16x32_bf16(a, b, c, 0, 0, 0)

// ---------------------------------------------------------------------------
// conv_in: out[b][n][o] = sum_c x[b][c][n] * w[o][c] + bias[o]   (fp32, unchanged)
// ---------------------------------------------------------------------------
__global__ __launch_bounds__(256) void conv_in(const float* __restrict__ x,
                                               const float* __restrict__ wgt,
                                               const float* __restrict__ bias,
                                               float* __restrict__ out) {
  __shared__ float Xs[16][64];  // [k][n]
  __shared__ float Ws[16][64];  // [k][o]
  const int b  = blockIdx.z;
  const int n0 = blockIdx.x * 64;
  const int o0 = blockIdx.y * 64;
  const int tid = threadIdx.x;
  const int tr = tid >> 4;
  const int tc = tid & 15;
  const int lk  = tid >> 4;
  const int ln4 = (tid & 15) << 2;
  const int lo  = tid >> 2;
  const int lk4 = (tid & 3) << 2;
  float acc[4][4] = {};
  for (int k0 = 0; k0 < NC; k0 += 16) {
    __syncthreads();
    *(float4*)&Xs[lk][ln4] =
        *(const float4*)(x + ((size_t)b * NC + k0 + lk) * NPOS + n0 + ln4);
    float4 wv = *(const float4*)(wgt + (size_t)(o0 + lo) * NC + k0 + lk4);
    Ws[lk4 + 0][lo] = wv.x; Ws[lk4 + 1][lo] = wv.y;
    Ws[lk4 + 2][lo] = wv.z; Ws[lk4 + 3][lo] = wv.w;
    __syncthreads();
#pragma unroll
    for (int k = 0; k < 16; ++k) {
      float4 a4 = *(const float4*)&Xs[k][tr << 2];
      float4 w4 = *(const float4*)&Ws[k][tc << 2];
      const float av[4] = {a4.x, a4.y, a4.z, a4.w};
      const float wvv[4] = {w4.x, w4.y, w4.z, w4.w};
#pragma unroll
      for (int i = 0; i < 4; ++i)
#pragma unroll
        for (int j = 0; j < 4; ++j) acc[i][j] = fmaf(av[i], wvv[j], acc[i][j]);
    }
  }
  float4 bv = *(const float4*)(bias + o0 + (tc << 2));
  const float bvv[4] = {bv.x, bv.y, bv.z, bv.w};
#pragma unroll
  for (int i = 0; i < 4; ++i) {
    float4 ov = make_float4(acc[i][0] + bvv[0], acc[i][1] + bvv[1],
                            acc[i][2] + bvv[2], acc[i][3] + bvv[3]);
    *(float4*)(out + ((size_t)b * NPOS + n0 + (tr << 2) + i) * NCI + o0 + (tc << 2)) = ov;
  }
}

// ---------------------------------------------------------------------------
// pool_split_phi: maxpool + split fp32 -> (hi, lo) bf16, layout (B, N', 256)
// ---------------------------------------------------------------------------
__global__ __launch_bounds__(256) void pool_split_phi(const float* __restrict__ full,
                                                      short* __restrict__ hi,
                                                      short* __restrict__ lo) {
  const int m = blockIdx.x;
  const int b = blockIdx.y;
  const int o = threadIdx.x;
  const int tp = m / 196;
  const int rr = m % 196;
  const int hp = rr / 14;
  const int wp = rr % 14;
  const size_t base = (size_t)b * NPOS * NCI;
  float best = -1e30f;
#pragma unroll
  for (int dt = 0; dt < 2; ++dt)
#pragma unroll
    for (int dh = 0; dh < 2; ++dh)
#pragma unroll
      for (int dw = 0; dw < 2; ++dw) {
        int n = (2 * tp + dt) * 784 + (2 * hp + dh) * 28 + (2 * wp + dw);
        best = fmaxf(best, full[base + (size_t)n * NCI + o]);
      }
  short h = f2bf(best);
  hi[((size_t)b * NPP + m) * NCI + o] = h;
  lo[((size_t)b * NPP + m) * NCI + o] = f2bf(best - bf2f(h));
}

// ---------------------------------------------------------------------------
// pool_g: maxpool -> bf16, TRANSPOSED layout (B, 256, N') for PV B-operand
// ---------------------------------------------------------------------------
__global__ __launch_bounds__(256) void pool_g(const float* __restrict__ full,
                                              short* __restrict__ gT) {
  const int m = blockIdx.x;
  const int b = blockIdx.y;
  const int o = threadIdx.x;
  const int tp = m / 196;
  const int rr = m % 196;
  const int hp = rr / 14;
  const int wp = rr % 14;
  const size_t base = (size_t)b * NPOS * NCI;
  float best = -1e30f;
#pragma unroll
  for (int dt = 0; dt < 2; ++dt)
#pragma unroll
    for (int dh = 0; dh < 2; ++dh)
#pragma unroll
      for (int dw = 0; dw < 2; ++dw) {
        int n = (2 * tp + dt) * 784 + (2 * hp + dh) * 28 + (2 * wp + dw);
        best = fmaxf(best, full[base + (size_t)n * NCI + o]);
      }
  gT[((size_t)b * NCI + o) * NPP + m] = f2bf(best);
}

// ---------------------------------------------------------------------------
// theta_split: fp32 theta -> hi/lo bf16 (elementwise)
// ---------------------------------------------------------------------------
__global__ __launch_bounds__(256) void theta_split(const float* __restrict__ src,
                                                   short* __restrict__ hi,
                                                   short* __restrict__ lo) {
  size_t i = ((size_t)blockIdx.x * 256 + threadIdx.x) * 4;
  float4 v = *(const float4*)(src + i);
  const float vv[4] = {v.x, v.y, v.z, v.w};
  s16x4 hv, lv;
#pragma unroll
  for (int j = 0; j < 4; ++j) {
    short h = f2bf(vv[j]);
    hv[j] = h;
    lv[j] = f2bf(vv[j] - bf2f(h));
  }
  *(s16x4*)(hi + i) = hv;
  *(s16x4*)(lo + i) = lv;
}

// ---------------------------------------------------------------------------
// attn_mfma: flash attention with split-bf16 QK^T (3 MFMA) + bf16 PV.
// Block: 256 thr = 4 waves, 64 q rows (16/wave), KV tile 64, k=256.
// LDS: phi_hi[64][128] 16K | phi_lo 16K | gT[256][64] 32K | P 4x2K = 72KB.
// All tiles XOR-swizzled: byte ^= (row&7)<<4 (write AND read).
// ---------------------------------------------------------------------------
__global__ __launch_bounds__(256) void attn_mfma(const short* __restrict__ thh,
                                                 const short* __restrict__ thl,
                                                 const short* __restrict__ phh,
                                                 const short* __restrict__ phl,
                                                 const short* __restrict__ gT,
                                                 float* __restrict__ y) {
  __shared__ char smem[73728];
  char* PH = smem;             // phi hi (current 128-k half)
  char* PL = smem + 16384;     // phi lo
  char* GB = smem + 32768;     // g transposed [256 c][64 m]
  const int tid = threadIdx.x;
  const int lane = tid & 63;
  const int wv = tid >> 6;
  char* PB = smem + 65536 + wv * 2048;   // per-wave P [16 q][64 m] bf16

  // XCD-aware swizzle: 784 = 8*98, each XCD gets a contiguous (b,q) chunk.
  const int id = blockIdx.x;
  const int lg = (id & 7) * 98 + (id >> 3);
  const int b = lg / 196;
  const int q0 = (lg % 196) * 64;
  const int l15 = lane & 15;
  const int lhi = lane >> 4;

  // Q fragments (hi+lo) resident in registers: 16 rows x 256 k per wave.
  bf16x8 qh[8], ql[8];
  {
    const size_t qb = ((size_t)b * NPOS + q0 + wv * 16 + l15) * 256 + lhi * 8;
#pragma unroll
    for (int s = 0; s < 8; ++s) {
      qh[s] = *(const bf16x8*)(thh + qb + s * 32);
      ql[s] = *(const bf16x8*)(thl + qb + s * 32);
    }
  }
  f32x4 yac[16];
#pragma unroll
  for (int i = 0; i < 16; ++i) yac[i] = (f32x4){0.f, 0.f, 0.f, 0.f};
  float rm[4] = {-1e30f, -1e30f, -1e30f, -1e30f};
  float rl[4] = {0.f, 0.f, 0.f, 0.f};

  for (int m0 = 0; m0 < NPP; m0 += 64) {
    f32x4 S[4];
#pragma unroll
    for (int j = 0; j < 4; ++j) S[j] = (f32x4){0.f, 0.f, 0.f, 0.f};
#pragma unroll
    for (int kh = 0; kh < 2; ++kh) {
      __syncthreads();   // protect phi bufs (and GB on kh==0) from prior readers
      // stage phi hi/lo for this k-half (64 m x 128 k bf16 each)
#pragma unroll
      for (int it = 0; it < 4; ++it) {
        int idx = tid + it * 256;          // 0..1023
        int mm = idx >> 4, kb = idx & 15;
        int msrc = m0 + mm; msrc = msrc < NPP ? msrc : NPP - 1;
        size_t ga = ((size_t)b * NPP + msrc) * 256 + kh * 128 + kb * 8;
        int lb = (mm * 256 + kb * 16) ^ ((mm & 7) << 4);
        *(bf16x8*)(PH + lb) = *(const bf16x8*)(phh + ga);
        *(bf16x8*)(PL + lb) = *(const bf16x8*)(phl + ga);
      }
      if (kh == 0) {
        // stage gT tile: [256 c][64 m] bf16
#pragma unroll
        for (int it = 0; it < 8; ++it) {
          int idx = tid + it * 256;        // 0..2047
          int c = idx >> 3, mb = idx & 7;
          size_t ga = ((size_t)b * NCI + c) * NPP + m0 + mb * 8;  // tail: slack-padded
          int lb = (c * 128 + mb * 16) ^ ((c & 7) << 4);
          *(bf16x8*)(GB + lb) = *(const bf16x8*)(gT + ga);
        }
      }
      __syncthreads();
      // QK^T for this k-half: S += Qh*Ph + Ql*Ph + Qh*Pl
#pragma unroll
      for (int s = 0; s < 4; ++s) {
        const int ss = kh * 4 + s;
#pragma unroll
        for (int fj = 0; fj < 4; ++fj) {
          int mrow = fj * 16 + l15;
          int lb = (mrow * 256 + s * 64 + lhi * 16) ^ ((mrow & 7) << 4);
          bf16x8 bh = *(const bf16x8*)(PH + lb);
          bf16x8 bl = *(const bf16x8*)(PL + lb);
          S[fj] = MFMA16(qh[ss], bh, S[fj]);
          S[fj] = MFMA16(ql[ss], bh, S[fj]);
          S[fj] = MFMA16(qh[ss], bl, S[fj]);
        }
      }
    }
    // tail mask: invalid kv columns -> -inf
    if (m0 + 64 > NPP) {
#pragma unroll
      for (int fj = 0; fj < 4; ++fj)
        if (m0 + fj * 16 + l15 >= NPP)
          S[fj] = (f32x4){-1e30f, -1e30f, -1e30f, -1e30f};
    }
    // online softmax; D-frag row = lhi*4 + r, col = fj*16 + l15
#pragma unroll
    for (int r = 0; r < 4; ++r) {
      float tm = fmaxf(fmaxf(S[0][r], S[1][r]), fmaxf(S[2][r], S[3][r]));
#pragma unroll
      for (int off = 8; off >= 1; off >>= 1) tm = fmaxf(tm, __shfl_xor(tm, off, 16));
      float nm = fmaxf(rm[r], tm);
      float sc = __expf(rm[r] - nm);
      float p0 = __expf(S[0][r] - nm);
      float p1 = __expf(S[1][r] - nm);
      float p2 = __expf(S[2][r] - nm);
      float p3 = __expf(S[3][r] - nm);
      float ps = p0 + p1 + p2 + p3;
#pragma unroll
      for (int off = 8; off >= 1; off >>= 1) ps += __shfl_xor(ps, off, 16);
      rl[r] = rl[r] * sc + ps;
      rm[r] = nm;
#pragma unroll
      for (int fc = 0; fc < 16; ++fc) yac[fc][r] *= sc;
      const int prow = lhi * 4 + r;
      const int rb = prow * 128;
      const int sx = (prow & 7) << 4;
      *(short*)(PB + ((rb + (0 * 16 + l15) * 2) ^ sx)) = f2bf(p0);
      *(short*)(PB + ((rb + (1 * 16 + l15) * 2) ^ sx)) = f2bf(p1);
      *(short*)(PB + ((rb + (2 * 16 + l15) * 2) ^ sx)) = f2bf(p2);
      *(short*)(PB + ((rb + (3 * 16 + l15) * 2) ^ sx)) = f2bf(p3);
    }
    // PV: yac += P * G   (wave-local P, no barrier needed)
#pragma unroll
    for (int ks = 0; ks < 2; ++ks) {
      int pb = (l15 * 128 + ks * 64 + lhi * 16) ^ ((l15 & 7) << 4);
      bf16x8 pa = *(const bf16x8*)(PB + pb);
#pragma unroll
      for (int fc = 0; fc < 16; ++fc) {
        int c = fc * 16 + l15;
        int gb = (c * 128 + ks * 64 + lhi * 16) ^ ((c & 7) << 4);
        bf16x8 gv = *(const bf16x8*)(GB + gb);
        yac[fc] = MFMA16(pa, gv, yac[fc]);
      }
    }
  }
  // epilogue: normalize and store y (B, N, 256) fp32
  float inv[4];
#pragma unroll
  for (int r = 0; r < 4; ++r) inv[r] = 1.f / rl[r];
  const size_t yb = ((size_t)b * NPOS + q0 + wv * 16 + lhi * 4) * 256 + l15;
#pragma unroll
  for (int fc = 0; fc < 16; ++fc)
#pragma unroll
    for (int r = 0; r < 4; ++r)
      y[yb + (size_t)r * 256 + fc * 16] = yac[fc][r] * inv[r];
}

// ---------------------------------------------------------------------------
// conv_out: out[b][o][n] = sum_ci w[o][ci] * y[b][n][ci] + bias[o]  (fp32)
// ---------------------------------------------------------------------------
__global__ __launch_bounds__(256) void conv_out(const float* __restrict__ wgt,
                                                const float* __restrict__ yv,
                                                const float* __restrict__ bias,
                                                float* __restrict__ out) {
  __shared__ float As[16][64];
  __shared__ float Bs[16][64];
  const int b  = blockIdx.z;
  const int n0 = blockIdx.x * 64;
  const int o0 = blockIdx.y * 64;
  const int tid = threadIdx.x;
  const int tr = tid >> 4;
  const int tc = tid & 15;
  const int lr  = tid >> 2;
  const int lk4 = (tid & 3) << 2;
  float acc[4][4] = {};
  for (int k0 = 0; k0 < NCI; k0 += 16) {
    __syncthreads();
    float4 wv = *(const float4*)(wgt + (size_t)(o0 + lr) * NCI + k0 + lk4);
    As[lk4 + 0][lr] = wv.x; As[lk4 + 1][lr] = wv.y;
    As[lk4 + 2][lr] = wv.z; As[lk4 + 3][lr] = wv.w;
    float4 yv4 = *(const float4*)(yv + ((size_t)b * NPOS + n0 + lr) * NCI + k0 + lk4);
    Bs[lk4 + 0][lr] = yv4.x; Bs[lk4 + 1][lr] = yv4.y;
    Bs[lk4 + 2][lr] = yv4.z; Bs[lk4 + 3][lr] = yv4.w;
    __syncthreads();
#pragma unroll
    for (int k = 0; k < 16; ++k) {
      float4 a4 = *(const float4*)&As[k][tr << 2];
      float4 b4 = *(const float4*)&Bs[k][tc << 2];
      const float av[4] = {a4.x, a4.y, a4.z, a4.w};
      const float bvv[4] = {b4.x, b4.y, b4.z, b4.w};
#pragma unroll
      for (int i = 0; i < 4; ++i)
#pragma unroll
        for (int j = 0; j < 4; ++j) acc[i][j] = fmaf(av[i], bvv[j], acc[i][j]);
    }
  }
#pragma unroll
  for (int i = 0; i < 4; ++i) {
    float bb = bias[o0 + (tr << 2) + i];
    float4 ov = make_float4(acc[i][0] + bb, acc[i][1] + bb,
                            acc[i][2] + bb, acc[i][3] + bb);
    *(float4*)(out + ((size_t)b * NC + o0 + (tr << 2) + i) * NPOS + n0 + (tc << 2)) = ov;
  }
}

// ---------------------------------------------------------------------------
__global__ __launch_bounds__(256) void bn_stats(const float* __restrict__ wy,
                                                const float* __restrict__ gamma,
                                                const float* __restrict__ beta,
                                                float* __restrict__ stats) {
  const int o = blockIdx.x;
  const int tid = threadIdx.x;
  double s = 0.0, ss = 0.0;
  for (int b = 0; b < NB; ++b) {
    const float* base = wy + ((size_t)b * NC + o) * NPOS;
    for (int n = tid; n < NPOS; n += 256) {
      float v = base[n];
      s += v;
      ss += (double)v * v;
    }
  }
  __shared__ double sd[256];
  __shared__ double ssd[256];
  sd[tid] = s; ssd[tid] = ss;
  __syncthreads();
  for (int w = 128; w > 0; w >>= 1) {
    if (tid < w) { sd[tid] += sd[tid + w]; ssd[tid] += ssd[tid + w]; }
    __syncthreads();
  }
  if (tid == 0) {
    const double M = (double)NB * NPOS;
    double mean = sd[0] / M;
    double var = ssd[0] / M - mean * mean;
    double inv = 1.0 / sqrt(var + 1e-5);
    float scale = (float)inv * gamma[o];
    float shift = beta[o] - (float)mean * scale;
    stats[o] = scale;
    stats[NC + o] = shift;
  }
}

__global__ __launch_bounds__(256) void bn_apply(float* __restrict__ out,
                                                const float* __restrict__ x,
                                                const float* __restrict__ stats) {
  const int bo = blockIdx.x;
  const int o = bo & (NC - 1);
  const float scale = stats[o];
  const float shift = stats[NC + o];
  const size_t base = (size_t)bo * NPOS;
  for (int n4 = (int)threadIdx.x * 4; n4 < NPOS; n4 += 256 * 4) {
    float4 v = *(const float4*)(out + base + n4);
    float4 xv = *(const float4*)(x + base + n4);
    v.x = v.x * scale + shift + xv.x;
    v.y = v.y * scale + shift + xv.y;
    v.z = v.z * scale + shift + xv.z;
    v.w = v.w * scale + shift + xv.w;
    *(float4*)(out + base + n4) = v;
  }
}

// ---------------------------------------------------------------------------
extern "C" void kernel_launch(void* const* d_in, const int* in_sizes, int n_in,
                              void* d_out, int out_size, void* d_ws, size_t ws_size,
                              hipStream_t stream) {
  const float* x     = (const float*)d_in[0];
  const float* g_w   = (const float*)d_in[1];
  const float* g_b   = (const float*)d_in[2];
  const float* th_w  = (const float*)d_in[3];
  const float* th_b  = (const float*)d_in[4];
  const float* ph_w  = (const float*)d_in[5];
  const float* ph_b  = (const float*)d_in[6];
  const float* W_w   = (const float*)d_in[7];
  const float* W_b   = (const float*)d_in[8];
  const float* gamma = (const float*)d_in[9];
  const float* beta  = (const float*)d_in[10];
  float* out = (float*)d_out;
  float* ws  = (float*)d_ws;

  const size_t SZ_BNC = (size_t)NB * NPOS * NCI;  // 12,845,056
  const size_t SZ_BPC = (size_t)NB * NPP * NCI;   //  1,605,632
  // ws layout (floats):
  //   A  [0, SZ_BNC)            : theta fp32, later y fp32
  //   Bf [SZ_BNC, 2*SZ_BNC)     : conv tmp fp32 (g-full, phi-full); later theta hi/lo bf16
  //   C  [2*SZ_BNC, ...)        : phi_hi, phi_lo, gT (bf16 shorts), stats
  float* A  = ws;
  float* Bf = ws + SZ_BNC;
  short* th_hi = (short*)Bf;
  short* th_lo = th_hi + SZ_BNC;              // 2*SZ_BNC shorts == SZ_BNC floats
  short* ph_hi = (short*)(ws + 2 * SZ_BNC);
  short* ph_lo = ph_hi + SZ_BPC;
  short* gTbuf = ph_lo + SZ_BPC;
  float* stats = (float*)(gTbuf + SZ_BPC + 64);  // +64 shorts slack for tail reads

  dim3 blk(256);
  dim3 gridC(NPOS / 64, NCI / 64, NB);     // (196, 4, 4)
  // g path -> gT (bf16, transposed)
  conv_in<<<gridC, blk, 0, stream>>>(x, g_w, g_b, Bf);
  pool_g<<<dim3(NPP, NB), blk, 0, stream>>>(Bf, gTbuf);
  // phi path -> hi/lo bf16
  conv_in<<<gridC, blk, 0, stream>>>(x, ph_w, ph_b, Bf);
  pool_split_phi<<<dim3(NPP, NB), blk, 0, stream>>>(Bf, ph_hi, ph_lo);
  // theta path -> fp32 then hi/lo bf16 (into Bf, now dead)
  conv_in<<<gridC, blk, 0, stream>>>(x, th_w, th_b, A);
  theta_split<<<dim3((int)(SZ_BNC / 1024)), blk, 0, stream>>>(A, th_hi, th_lo);
  // attention (writes y into A, theta fp32 dead)
  attn_mfma<<<dim3(784), blk, 0, stream>>>(th_hi, th_lo, ph_hi, ph_lo, gTbuf, A);
  // output conv + BN + residual
  conv_out<<<dim3(NPOS / 64, NC / 64, NB), blk, 0, stream>>>(W_w, A, W_b, out);
  bn_stats<<<dim3(NC), blk, 0, stream>>>(out, gamma, beta, stats);
  bn_apply<<<dim3(NB * NC), blk, 0, stream>>>(out, x, stats);
}

// Round 4
// 1171.032 us; speedup vs baseline: 2.6590x; 1.3002x over previous
//
#include <hip/hip_runtime.h>
#include <hip/hip_bf16.h>

#define NB   4
#define NC   512
#define NCI  256
#define NPOS 12544   // 16*28*28
#define NPP  1568    // 8*14*14

typedef __attribute__((ext_vector_type(8))) short bf16x8;
typedef __attribute__((ext_vector_type(4))) short s16x4;
typedef __attribute__((ext_vector_type(4))) float f32x4;

__device__ __forceinline__ short f2bf(float f) {
  union { __hip_bfloat16 b; short s; } u;
  u.b = __float2bfloat16(f);
  return u.s;
}
__device__ __forceinline__ float bf2f(short s) {
  union { short s; __hip_bfloat16 b; } u;
  u.s = s;
  return __bfloat162float(u.b);
}

#define MFMA16(a, b, c) __builtin_amdgcn_mfma_f32_16x16x32_bf16(a, b, c, 0, 0, 0)

// ---------------------------------------------------------------------------
// wsplit: split the 4 weight arrays (each 131072 floats, c-fastest) -> hi/lo
// slots: 0=g_w, 1=theta_w, 2=phi_w, 3=W_w
// ---------------------------------------------------------------------------
__global__ __launch_bounds__(256) void wsplit(const float* __restrict__ s0,
                                              const float* __restrict__ s1,
                                              const float* __restrict__ s2,
                                              const float* __restrict__ s3,
                                              short* __restrict__ hi,
                                              short* __restrict__ lo) {
  const float* src = (blockIdx.y == 0) ? s0 : (blockIdx.y == 1) ? s1
                     : (blockIdx.y == 2) ? s2 : s3;
  const size_t base = (size_t)blockIdx.y * 131072;
  const size_t i = ((size_t)blockIdx.x * 256 + threadIdx.x) * 4;
  float4 v = *(const float4*)(src + i);
  const float vv[4] = {v.x, v.y, v.z, v.w};
  s16x4 h, l;
#pragma unroll
  for (int j = 0; j < 4; ++j) {
    h[j] = f2bf(vv[j]);
    l[j] = f2bf(vv[j] - bf2f(h[j]));
  }
  *(s16x4*)(hi + base + i) = h;
  *(s16x4*)(lo + base + i) = l;
}

// ---------------------------------------------------------------------------
// conv3: transposed-output 1x1 conv via split-bf16 MFMA.
// out[b][o][n] = sum_c w[o][c]*x[b][c][n] + bias[o], out layout (B,256,N).
// Block 256 thr = 4 waves; wave = 64o x 64n (fi: o-frags, fj: n-frags).
// A = w (hi/lo staged globally), B = x fp32 loaded strided + split in-register
// (trunc-hi + RNE-lo: pair err 2^-17). No LDS, no barriers.
// ---------------------------------------------------------------------------
__global__ __launch_bounds__(256) void conv3(const float* __restrict__ x,
                                             const short* __restrict__ wh,
                                             const short* __restrict__ wl,
                                             const float* __restrict__ bias,
                                             short* __restrict__ outh,
                                             short* __restrict__ outl,
                                             int writeLo) {
  const int b  = blockIdx.y;
  const int n0 = blockIdx.x * 64;
  const int tid = threadIdx.x;
  const int lane = tid & 63;
  const int wv = tid >> 6;
  const int l15 = lane & 15, lhi = lane >> 4;
  const size_t xb = (size_t)b * NC * NPOS;

  f32x4 acc[4][4];
#pragma unroll
  for (int fi = 0; fi < 4; ++fi)
#pragma unroll
    for (int fj = 0; fj < 4; ++fj) acc[fi][fj] = (f32x4){0.f, 0.f, 0.f, 0.f};

#pragma unroll 2
  for (int s = 0; s < 16; ++s) {
    bf16x8 ah[4], al[4], bh[4], bl[4];
#pragma unroll
    for (int fi = 0; fi < 4; ++fi) {
      const int o = wv * 64 + fi * 16 + l15;
      const size_t wa = (size_t)o * 512 + s * 32 + lhi * 8;
      ah[fi] = *(const bf16x8*)(wh + wa);
      al[fi] = *(const bf16x8*)(wl + wa);
    }
#pragma unroll
    for (int fj = 0; fj < 4; ++fj) {
      const int n = n0 + fj * 16 + l15;
      const float* xp = x + xb + (size_t)(s * 32 + lhi * 8) * NPOS + n;
      bf16x8 h, l;
#pragma unroll
      for (int e = 0; e < 8; ++e) {
        float v = xp[(size_t)e * NPOS];
        unsigned u = __float_as_uint(v);
        float hf = __uint_as_float(u & 0xFFFF0000u);
        h[e] = (short)(u >> 16);
        l[e] = f2bf(v - hf);
      }
      bh[fj] = h; bl[fj] = l;
    }
#pragma unroll
    for (int fi = 0; fi < 4; ++fi)
#pragma unroll
      for (int fj = 0; fj < 4; ++fj) {
        acc[fi][fj] = MFMA16(ah[fi], bh[fj], acc[fi][fj]);
        acc[fi][fj] = MFMA16(al[fi], bh[fj], acc[fi][fj]);
        acc[fi][fj] = MFMA16(ah[fi], bl[fj], acc[fi][fj]);
      }
  }
  // epilogue: +bias, split to bf16 hi/lo, store transposed (B,256,N)
  const size_t ob = (size_t)b * NCI * NPOS;
#pragma unroll
  for (int fi = 0; fi < 4; ++fi)
#pragma unroll
    for (int r = 0; r < 4; ++r) {
      const int o = wv * 64 + fi * 16 + lhi * 4 + r;
      const float bb = bias[o];
      const size_t rowb = ob + (size_t)o * NPOS + n0 + l15;
#pragma unroll
      for (int fj = 0; fj < 4; ++fj) {
        float v = acc[fi][fj][r] + bb;
        short hh = f2bf(v);
        outh[rowb + fj * 16] = hh;
        if (writeLo) outl[rowb + fj * 16] = f2bf(v - bf2f(hh));
      }
    }
}

// ---------------------------------------------------------------------------
// pool_gT: maxpool along n in transposed layout (B,256,N)->(B,256,N') bf16
// ---------------------------------------------------------------------------
__global__ __launch_bounds__(256) void pool_gT(const short* __restrict__ gf,
                                               short* __restrict__ gT) {
  const int c = blockIdx.x, b = blockIdx.y;
  const size_t rb = ((size_t)b * NCI + c) * NPOS;
  const size_t ob = ((size_t)b * NCI + c) * NPP;
  for (int m = threadIdx.x; m < NPP; m += 256) {
    int tp = m / 196, rr = m % 196, hp = rr / 14, wp = rr % 14;
    int nb_ = 2 * tp * 784 + 2 * hp * 28 + 2 * wp;
    float best = -1e30f; short bs = 0;
#pragma unroll
    for (int dt = 0; dt < 2; ++dt)
#pragma unroll
      for (int dh = 0; dh < 2; ++dh)
#pragma unroll
        for (int dw = 0; dw < 2; ++dw) {
          short sv = gf[rb + nb_ + dt * 784 + dh * 28 + dw];
          float v = bf2f(sv);
          if (v > best) { best = v; bs = sv; }
        }
    gT[ob + m] = bs;
  }
}

// ---------------------------------------------------------------------------
// pool_phi: maxpool + transpose: phiT-full (B,256,N) hi/lo -> (B,N',256) hi/lo
// Block: 64 m x 64 c, LDS transpose. Max chosen by reconstructed value hi+lo
// (monotone: the argmax's (hi,lo) pair IS its split).
// ---------------------------------------------------------------------------
__global__ __launch_bounds__(256) void pool_phi(const short* __restrict__ fh,
                                                const short* __restrict__ fl,
                                                short* __restrict__ ph,
                                                short* __restrict__ pl) {
  __shared__ unsigned plds[64][65];
  const int m0 = blockIdx.x * 64;
  const int c0 = blockIdx.y * 64;
  const int b = blockIdx.z;
  const int tid = threadIdx.x;
  const int ml = tid & 63, cq = tid >> 6;
  const int m = m0 + ml;
  if (m < NPP) {
    int tp = m / 196, rr = m % 196, hp = rr / 14, wp = rr % 14;
    int nb_ = 2 * tp * 784 + 2 * hp * 28 + 2 * wp;
    for (int cc = cq; cc < 64; cc += 4) {
      const size_t rb = ((size_t)b * NCI + c0 + cc) * NPOS + nb_;
      float best = -1e30f; unsigned bestp = 0;
#pragma unroll
      for (int dt = 0; dt < 2; ++dt)
#pragma unroll
        for (int dh = 0; dh < 2; ++dh)
#pragma unroll
          for (int dw = 0; dw < 2; ++dw) {
            size_t a = rb + dt * 784 + dh * 28 + dw;
            unsigned short hh = (unsigned short)fh[a];
            unsigned short ll = (unsigned short)fl[a];
            float v = bf2f((short)hh) + bf2f((short)ll);
            if (v > best) { best = v; bestp = (unsigned)hh | ((unsigned)ll << 16); }
          }
      plds[ml][cc] = bestp;
    }
  }
  __syncthreads();
  const int ml2 = tid >> 2, cs = (tid & 3) * 16;
  if (m0 + ml2 < NPP) {
    const size_t obase = ((size_t)b * NPP + m0 + ml2) * NCI + c0 + cs;
#pragma unroll
    for (int i = 0; i < 16; i += 8) {
      bf16x8 H, L;
#pragma unroll
      for (int j = 0; j < 8; ++j) {
        unsigned u = plds[ml2][cs + i + j];
        H[j] = (short)(u & 0xFFFFu);
        L[j] = (short)(u >> 16);
      }
      *(bf16x8*)(ph + obase + i) = H;
      *(bf16x8*)(pl + obase + i) = L;
    }
  }
}

// ---------------------------------------------------------------------------
// attn_mfma: flash attention, split-bf16 QK^T (3 MFMA) + bf16 PV.
// Q now read from transposed theta (B,256,N) (one-time scalar loads);
// y written as bf16 hi/lo (B,N,256) for the MFMA output conv.
// Core loop identical to round 3 (verified).
// ---------------------------------------------------------------------------
__global__ __launch_bounds__(256) void attn_mfma(const short* __restrict__ thh,
                                                 const short* __restrict__ thl,
                                                 const short* __restrict__ phh,
                                                 const short* __restrict__ phl,
                                                 const short* __restrict__ gT,
                                                 short* __restrict__ yh,
                                                 short* __restrict__ yl) {
  __shared__ char smem[73728];
  char* PH = smem;             // phi hi (current 128-k half)
  char* PL = smem + 16384;     // phi lo
  char* GB = smem + 32768;     // g transposed [256 c][64 m]
  const int tid = threadIdx.x;
  const int lane = tid & 63;
  const int wv = tid >> 6;
  char* PB = smem + 65536 + wv * 2048;   // per-wave P [16 q][64 m] bf16

  const int id = blockIdx.x;
  const int lg = (id & 7) * 98 + (id >> 3);
  const int b = lg / 196;
  const int q0 = (lg % 196) * 64;
  const int l15 = lane & 15;
  const int lhi = lane >> 4;

  // Q fragments (hi+lo) from theta^T: 16 rows x 256 k per wave (one-time).
  bf16x8 qh[8], ql[8];
  {
    const size_t qcol = (size_t)b * NCI * NPOS + (q0 + wv * 16 + l15);
#pragma unroll
    for (int s = 0; s < 8; ++s) {
      bf16x8 h, l;
#pragma unroll
      for (int e = 0; e < 8; ++e) {
        size_t a = qcol + (size_t)(s * 32 + lhi * 8 + e) * NPOS;
        h[e] = thh[a];
        l[e] = thl[a];
      }
      qh[s] = h; ql[s] = l;
    }
  }
  f32x4 yac[16];
#pragma unroll
  for (int i = 0; i < 16; ++i) yac[i] = (f32x4){0.f, 0.f, 0.f, 0.f};
  float rm[4] = {-1e30f, -1e30f, -1e30f, -1e30f};
  float rl[4] = {0.f, 0.f, 0.f, 0.f};

  for (int m0 = 0; m0 < NPP; m0 += 64) {
    f32x4 S[4];
#pragma unroll
    for (int j = 0; j < 4; ++j) S[j] = (f32x4){0.f, 0.f, 0.f, 0.f};
#pragma unroll
    for (int kh = 0; kh < 2; ++kh) {
      __syncthreads();
#pragma unroll
      for (int it = 0; it < 4; ++it) {
        int idx = tid + it * 256;          // 0..1023
        int mm = idx >> 4, kb = idx & 15;
        int msrc = m0 + mm; msrc = msrc < NPP ? msrc : NPP - 1;
        size_t ga = ((size_t)b * NPP + msrc) * 256 + kh * 128 + kb * 8;
        int lb = (mm * 256 + kb * 16) ^ ((mm & 7) << 4);
        *(bf16x8*)(PH + lb) = *(const bf16x8*)(phh + ga);
        *(bf16x8*)(PL + lb) = *(const bf16x8*)(phl + ga);
      }
      if (kh == 0) {
#pragma unroll
        for (int it = 0; it < 8; ++it) {
          int idx = tid + it * 256;        // 0..2047
          int c = idx >> 3, mb = idx & 7;
          size_t ga = ((size_t)b * NCI + c) * NPP + m0 + mb * 8;  // tail: slack
          int lb = (c * 128 + mb * 16) ^ ((c & 7) << 4);
          *(bf16x8*)(GB + lb) = *(const bf16x8*)(gT + ga);
        }
      }
      __syncthreads();
#pragma unroll
      for (int s = 0; s < 4; ++s) {
        const int ss = kh * 4 + s;
#pragma unroll
        for (int fj = 0; fj < 4; ++fj) {
          int mrow = fj * 16 + l15;
          int lb = (mrow * 256 + s * 64 + lhi * 16) ^ ((mrow & 7) << 4);
          bf16x8 bh = *(const bf16x8*)(PH + lb);
          bf16x8 bl = *(const bf16x8*)(PL + lb);
          S[fj] = MFMA16(qh[ss], bh, S[fj]);
          S[fj] = MFMA16(ql[ss], bh, S[fj]);
          S[fj] = MFMA16(qh[ss], bl, S[fj]);
        }
      }
    }
    if (m0 + 64 > NPP) {
#pragma unroll
      for (int fj = 0; fj < 4; ++fj)
        if (m0 + fj * 16 + l15 >= NPP)
          S[fj] = (f32x4){-1e30f, -1e30f, -1e30f, -1e30f};
    }
#pragma unroll
    for (int r = 0; r < 4; ++r) {
      float tm = fmaxf(fmaxf(S[0][r], S[1][r]), fmaxf(S[2][r], S[3][r]));
#pragma unroll
      for (int off = 8; off >= 1; off >>= 1) tm = fmaxf(tm, __shfl_xor(tm, off, 16));
      float nm = fmaxf(rm[r], tm);
      float sc = __expf(rm[r] - nm);
      float p0 = __expf(S[0][r] - nm);
      float p1 = __expf(S[1][r] - nm);
      float p2 = __expf(S[2][r] - nm);
      float p3 = __expf(S[3][r] - nm);
      float ps = p0 + p1 + p2 + p3;
#pragma unroll
      for (int off = 8; off >= 1; off >>= 1) ps += __shfl_xor(ps, off, 16);
      rl[r] = rl[r] * sc + ps;
      rm[r] = nm;
#pragma unroll
      for (int fc = 0; fc < 16; ++fc) yac[fc][r] *= sc;
      const int prow = lhi * 4 + r;
      const int rb = prow * 128;
      const int sx = (prow & 7) << 4;
      *(short*)(PB + ((rb + (0 * 16 + l15) * 2) ^ sx)) = f2bf(p0);
      *(short*)(PB + ((rb + (1 * 16 + l15) * 2) ^ sx)) = f2bf(p1);
      *(short*)(PB + ((rb + (2 * 16 + l15) * 2) ^ sx)) = f2bf(p2);
      *(short*)(PB + ((rb + (3 * 16 + l15) * 2) ^ sx)) = f2bf(p3);
    }
#pragma unroll
    for (int ks = 0; ks < 2; ++ks) {
      int pb = (l15 * 128 + ks * 64 + lhi * 16) ^ ((l15 & 7) << 4);
      bf16x8 pa = *(const bf16x8*)(PB + pb);
#pragma unroll
      for (int fc = 0; fc < 16; ++fc) {
        int c = fc * 16 + l15;
        int gb = (c * 128 + ks * 64 + lhi * 16) ^ ((c & 7) << 4);
        bf16x8 gv = *(const bf16x8*)(GB + gb);
        yac[fc] = MFMA16(pa, gv, yac[fc]);
      }
    }
  }
  float inv[4];
#pragma unroll
  for (int r = 0; r < 4; ++r) inv[r] = 1.f / rl[r];
  const size_t yb = ((size_t)b * NPOS + q0 + wv * 16 + lhi * 4) * NCI + l15;
#pragma unroll
  for (int fc = 0; fc < 16; ++fc)
#pragma unroll
    for (int r = 0; r < 4; ++r) {
      float v = yac[fc][r] * inv[r];
      short hh = f2bf(v);
      yh[yb + (size_t)r * NCI + fc * 16] = hh;
      yl[yb + (size_t)r * NCI + fc * 16] = f2bf(v - bf2f(hh));
    }
}

// ---------------------------------------------------------------------------
// conv_out_mfma: out[b][o][n] = sum_ci W[o][ci]*y[b][n][ci] + bias[o]
// Split-bf16 MFMA; fused BN partial sums via atomicAdd into stats[0..1023].
// Block 256 thr = 4 waves; wave = 64o x 64n; grid (196 n-tiles, 2 o-halves, B).
// ---------------------------------------------------------------------------
__global__ __launch_bounds__(256) void conv_out_mfma(const short* __restrict__ wh,
                                                     const short* __restrict__ wl,
                                                     const short* __restrict__ yh,
                                                     const short* __restrict__ yl,
                                                     const float* __restrict__ bias,
                                                     float* __restrict__ out,
                                                     float* __restrict__ stats) {
  const int b  = blockIdx.z;
  const int oh = blockIdx.y;
  const int n0 = blockIdx.x * 64;
  const int tid = threadIdx.x;
  const int lane = tid & 63;
  const int wv = tid >> 6;
  const int l15 = lane & 15, lhi = lane >> 4;
  const int obase = oh * 256 + wv * 64;

  f32x4 acc[4][4];
#pragma unroll
  for (int fi = 0; fi < 4; ++fi)
#pragma unroll
    for (int fj = 0; fj < 4; ++fj) acc[fi][fj] = (f32x4){0.f, 0.f, 0.f, 0.f};

#pragma unroll 2
  for (int s = 0; s < 8; ++s) {
    bf16x8 ah[4], al[4], bh[4], bl[4];
#pragma unroll
    for (int fi = 0; fi < 4; ++fi) {
      const int o = obase + fi * 16 + l15;
      const size_t wa = (size_t)o * 256 + s * 32 + lhi * 8;
      ah[fi] = *(const bf16x8*)(wh + wa);
      al[fi] = *(const bf16x8*)(wl + wa);
    }
#pragma unroll
    for (int fj = 0; fj < 4; ++fj) {
      const int n = n0 + fj * 16 + l15;
      const size_t ya = ((size_t)b * NPOS + n) * NCI + s * 32 + lhi * 8;
      bh[fj] = *(const bf16x8*)(yh + ya);
      bl[fj] = *(const bf16x8*)(yl + ya);
    }
#pragma unroll
    for (int fi = 0; fi < 4; ++fi)
#pragma unroll
      for (int fj = 0; fj < 4; ++fj) {
        acc[fi][fj] = MFMA16(ah[fi], bh[fj], acc[fi][fj]);
        acc[fi][fj] = MFMA16(al[fi], bh[fj], acc[fi][fj]);
        acc[fi][fj] = MFMA16(ah[fi], bl[fj], acc[fi][fj]);
      }
  }
  // epilogue: +bias, store (B,512,N), accumulate BN sum/sumsq atomics
#pragma unroll
  for (int fi = 0; fi < 4; ++fi)
#pragma unroll
    for (int r = 0; r < 4; ++r) {
      const int o = obase + fi * 16 + lhi * 4 + r;
      const float bb = bias[o];
      const size_t rowb = ((size_t)b * NC + o) * NPOS + n0 + l15;
      float sa = 0.f, sq = 0.f;
#pragma unroll
      for (int fj = 0; fj < 4; ++fj) {
        float v = acc[fi][fj][r] + bb;
        out[rowb + fj * 16] = v;
        sa += v;
        sq += v * v;
      }
#pragma unroll
      for (int off = 8; off >= 1; off >>= 1) {
        sa += __shfl_xor(sa, off, 16);
        sq += __shfl_xor(sq, off, 16);
      }
      if (l15 == 0) {
        atomicAdd(&stats[o], sa);
        atomicAdd(&stats[512 + o], sq);
      }
    }
}

// ---------------------------------------------------------------------------
__global__ __launch_bounds__(256) void bn_finalize(const float* __restrict__ gamma,
                                                   const float* __restrict__ beta,
                                                   float* __restrict__ stats) {
  const int o = blockIdx.x * 256 + threadIdx.x;
  const float M = (float)(NB * NPOS);
  float mean = stats[o] / M;
  float var = stats[512 + o] / M - mean * mean;
  float inv = 1.f / sqrtf(var + 1e-5f);
  float scale = inv * gamma[o];
  float shift = beta[o] - mean * scale;
  stats[1024 + o] = scale;
  stats[1536 + o] = shift;
}

__global__ __launch_bounds__(256) void bn_apply(float* __restrict__ out,
                                                const float* __restrict__ x,
                                                const float* __restrict__ stats) {
  const int bo = blockIdx.x;
  const int o = bo & (NC - 1);
  const float scale = stats[1024 + o];
  const float shift = stats[1536 + o];
  const size_t base = (size_t)bo * NPOS;
  for (int n4 = (int)threadIdx.x * 4; n4 < NPOS; n4 += 256 * 4) {
    float4 v = *(const float4*)(out + base + n4);
    float4 xv = *(const float4*)(x + base + n4);
    v.x = v.x * scale + shift + xv.x;
    v.y = v.y * scale + shift + xv.y;
    v.z = v.z * scale + shift + xv.z;
    v.w = v.w * scale + shift + xv.w;
    *(float4*)(out + base + n4) = v;
  }
}

// ---------------------------------------------------------------------------
extern "C" void kernel_launch(void* const* d_in, const int* in_sizes, int n_in,
                              void* d_out, int out_size, void* d_ws, size_t ws_size,
                              hipStream_t stream) {
  const float* x     = (const float*)d_in[0];
  const float* g_w   = (const float*)d_in[1];
  const float* g_b   = (const float*)d_in[2];
  const float* th_w  = (const float*)d_in[3];
  const float* th_b  = (const float*)d_in[4];
  const float* ph_w  = (const float*)d_in[5];
  const float* ph_b  = (const float*)d_in[6];
  const float* W_w   = (const float*)d_in[7];
  const float* W_b   = (const float*)d_in[8];
  const float* gamma = (const float*)d_in[9];
  const float* beta  = (const float*)d_in[10];
  float* out = (float*)d_out;

  const size_t SZT = (size_t)NB * NPOS * 256;  // 12,845,056 shorts
  const size_t SZP = (size_t)NB * NPP * 256;   //  1,605,632 shorts
  short* thTh = (short*)d_ws;        // theta^T hi   (B,256,N)
  short* thTl = thTh + SZT;          // theta^T lo
  short* regA = thTh + 2 * SZT;      // gT-full -> phiT-full hi -> y hi
  short* regB = thTh + 3 * SZT;      //            phiT-full lo -> y lo
  short* phph = thTh + 4 * SZT;      // pooled phi hi (B,N',256)
  short* phpl = phph + SZP;
  short* gTp  = phpl + SZP;          // pooled gT (B,256,N') + slack
  short* whb  = gTp + SZP + 128;     // weight hi: slots g,theta,phi,W
  short* wlb  = whb + 524288;
  float* stats = (float*)(wlb + 524288);  // 2048 floats

  hipMemsetAsync(stats, 0, 1024 * sizeof(float), stream);

  dim3 blk(256);
  wsplit<<<dim3(128, 4), blk, 0, stream>>>(g_w, th_w, ph_w, W_w, whb, wlb);
  // g path (transposed full-res, hi only) -> pool along n
  conv3<<<dim3(196, NB), blk, 0, stream>>>(x, whb, wlb, g_b, regA, regB, 0);
  pool_gT<<<dim3(256, NB), blk, 0, stream>>>(regA, gTp);
  // phi path (transposed full-res hi/lo) -> pool + transpose to (B,N',256)
  conv3<<<dim3(196, NB), blk, 0, stream>>>(x, whb + 2 * 131072, wlb + 2 * 131072,
                                           ph_b, regA, regB, 1);
  pool_phi<<<dim3(25, 4, NB), blk, 0, stream>>>(regA, regB, phph, phpl);
  // theta path (transposed, hi/lo) -- consumed by attn as Q
  conv3<<<dim3(196, NB), blk, 0, stream>>>(x, whb + 1 * 131072, wlb + 1 * 131072,
                                           th_b, thTh, thTl, 1);
  // attention -> y (bf16 hi/lo) into regA/regB (phiT-full dead)
  attn_mfma<<<dim3(784), blk, 0, stream>>>(thTh, thTl, phph, phpl, gTp, regA, regB);
  // output conv (+ fused BN partial sums) + BN finalize + apply
  conv_out_mfma<<<dim3(196, 2, NB), blk, 0, stream>>>(whb + 3 * 131072,
                                                      wlb + 3 * 131072,
                                                      regA, regB, W_b, out, stats);
  bn_finalize<<<dim3(2), blk, 0, stream>>>(gamma, beta, stats);
  bn_apply<<<dim3(NB * NC), blk, 0, stream>>>(out, x, stats);
}